// Round 2
// baseline (296.267 us; speedup 1.0000x reference)
//
#include <hip/hip_runtime.h>

// HelixMemory, fp32 I/O.
// out rows 510..2557 = raw copy: memory[512:2558] ++ inputs[0:2]  (out row r <- new_memory row r+2)
// out rows 0..509    = binary avg-pool hierarchy over memory rows 1024..1535 only:
//   P_l[i] = mean of 2^l consecutive "fallout" rows (fallout row t = memory row 512+t).
//   rows 254..381: P1[384..512) ; 382..509: P2[128..256) ; 126..189: P2[192..256)
//   190..253: P3[64..128) ; 62..93: P3[96..128) ; 94..125: P4[32..64) ; 30..45: P4[48..64)
//   level l>=5: primary row = 2^(10-l)-2+i for i in [2^(9-l),2^(10-l)),
//               secondary row = 2^(9-l)-2+i-3*2^(8-l) when i >= 3*2^(8-l) (l<9), plus P9[1] -> row 1.
// Pairwise-sum tree + single 2^-l scale == reference's nested /2 bitwise (halving exact).

typedef __attribute__((ext_vector_type(4))) float f32x4;

#define B_    8
#define D_    2048
#define MEMR_ 2558
#define OUTR_ 2558
#define INR_  1024

#define POOL_DT     64                     // 64 col-tiles of 32 floats
#define POOL_BLOCKS (B_ * POOL_DT)         // 512
#define COPY_BLOCKS 32768                  // 8 * 2048 rows * 512 float4 / 256 thr

__device__ __forceinline__ void write_row(float* dst, const float* s, float scale) {
  f32x4 o;
#pragma unroll
  for (int e = 0; e < 4; ++e) o[e] = s[e] * scale;
  *reinterpret_cast<f32x4*>(dst) = o;
}

__global__ __launch_bounds__(256) void helix_kernel(
    const float* __restrict__ inputs,
    const float* __restrict__ memory,
    float* __restrict__ out) {
  __shared__ float lds[32 * 32];
  const int bid = blockIdx.x;
  const int tid = threadIdx.x;

  if (bid < POOL_BLOCKS) {
    // ---- pool-tree blocks: one (batch, 32-column tile) each ----
    const int b  = bid >> 6;           // / POOL_DT
    const int dt = bid & 63;
    const int q  = tid >> 3;           // 0..31 : row-group (16 fallout rows each)
    const int c  = tid & 7;            // 0..7  : float4 column within tile
    const int dcol = dt * 32 + c * 4;

    // tree source: fallout rows 512..1023 == memory rows 1024..1535
    const float* fall = memory + ((long)b * MEMR_ + 1024) * D_ + dcol;
    float* ob = out + (long)b * OUTR_ * D_ + dcol;

    float f[4], s1[4], s2[4], s3[4], s4[4];
    const float* rp = fall + (long)(q * 16) * D_;

#pragma unroll
    for (int j = 0; j < 16; ++j) {
      f32x4 u = *reinterpret_cast<const f32x4*>(rp + (long)j * D_);
#pragma unroll
      for (int e = 0; e < 4; ++e) f[e] = u[e];
      if ((j & 1) == 0) {
#pragma unroll
        for (int e = 0; e < 4; ++e) s1[e] = f[e];
      } else {
#pragma unroll
        for (int e = 0; e < 4; ++e) s1[e] += f[e];
        const int i1 = 256 + 8 * q + (j >> 1);            // P1 index in [256,512)
        if (i1 >= 384) write_row(ob + (long)(i1 - 130) * D_, s1, 0.5f);
        if ((j & 3) == 1) {
#pragma unroll
          for (int e = 0; e < 4; ++e) s2[e] = s1[e];
        } else {
#pragma unroll
          for (int e = 0; e < 4; ++e) s2[e] += s1[e];
          const int i2 = 128 + 4 * q + (j >> 2);          // P2 in [128,256)
          write_row(ob + (long)(254 + i2) * D_, s2, 0.25f);
          if (i2 >= 192) write_row(ob + (long)(i2 - 66) * D_, s2, 0.25f);
          if ((j & 7) == 3) {
#pragma unroll
            for (int e = 0; e < 4; ++e) s3[e] = s2[e];
          } else {
#pragma unroll
            for (int e = 0; e < 4; ++e) s3[e] += s2[e];
            const int i3 = 64 + 2 * q + (j >> 3);         // P3 in [64,128)
            write_row(ob + (long)(126 + i3) * D_, s3, 0.125f);
            if (i3 >= 96) write_row(ob + (long)(i3 - 34) * D_, s3, 0.125f);
            if (j == 7) {
#pragma unroll
              for (int e = 0; e < 4; ++e) s4[e] = s3[e];
            } else if (j == 15) {
#pragma unroll
              for (int e = 0; e < 4; ++e) s4[e] += s3[e];
              const int i4 = 32 + q;                      // P4 in [32,64)
              write_row(ob + (long)(62 + i4) * D_, s4, 0.0625f);
              if (i4 >= 48) write_row(ob + (long)(i4 - 18) * D_, s4, 0.0625f);
            }
          }
        }
      }
    }

    // stash 16-row sums, then LDS tree for levels 5..9
    float* myl = lds + q * 32 + c * 4;
#pragma unroll
    for (int e = 0; e < 4; ++e) myl[e] = s4[e];

    int nq = 16;
    float scale = 1.0f / 32.0f;
    for (int l = 5; l <= 9; ++l) {
      __syncthreads();
      float a[4], bb[4];
      const bool act = (q < nq);
      if (act) {
#pragma unroll
        for (int e = 0; e < 4; ++e) {
          a[e]  = lds[(2 * q) * 32 + c * 4 + e];
          bb[e] = lds[(2 * q + 1) * 32 + c * 4 + e];
        }
      }
      __syncthreads();
      if (act) {
#pragma unroll
        for (int e = 0; e < 4; ++e) a[e] += bb[e];
#pragma unroll
        for (int e = 0; e < 4; ++e) lds[q * 32 + c * 4 + e] = a[e];
        const int i = nq + q;                              // P_l index in [2^(9-l), 2^(10-l))
        write_row(ob + (long)((1 << (10 - l)) - 2 + i) * D_, a, scale);
        if (l < 9 && i >= (3 << (8 - l)))
          write_row(ob + (long)((1 << (9 - l)) - 2 + i - (3 << (8 - l))) * D_, a, scale);
      }
      nq >>= 1;
      scale *= 0.5f;
    }
  } else {
    // ---- copy blocks: out rows 510..2557 ----
    const long v   = (long)(bid - POOL_BLOCKS) * 256 + tid;   // float4 id
    const int  b   = (int)(v >> 20);                          // / (2048 rows * 512 f4)
    const int  rem = (int)(v & ((1 << 20) - 1));
    const int  j   = rem >> 9;                                // row within short_memory
    const int  dv  = rem & 511;                               // float4 within row
    const float* src = (j < 2046)
        ? memory + ((long)b * MEMR_ + 512 + j) * D_ + dv * 4
        : inputs + ((long)b * INR_ + (j - 2046)) * D_ + dv * 4;
    float* dst = out + ((long)b * OUTR_ + 510 + j) * D_ + dv * 4;
    *reinterpret_cast<f32x4*>(dst) = *reinterpret_cast<const f32x4*>(src);
  }
}

extern "C" void kernel_launch(void* const* d_in, const int* in_sizes, int n_in,
                              void* d_out, int out_size, void* d_ws, size_t ws_size,
                              hipStream_t stream) {
  const float* inputs = (const float*)d_in[0];
  const float* memory = (const float*)d_in[1];
  float* out = (float*)d_out;
  helix_kernel<<<dim3(POOL_BLOCKS + COPY_BLOCKS), dim3(256), 0, stream>>>(inputs, memory, out);
}

// Round 3
// 295.988 us; speedup vs baseline: 1.0009x; 1.0009x over previous
//
#include <hip/hip_runtime.h>

// HelixMemory, fp32 I/O.
// out rows 510..2557 = raw copy: memory[512:2558] ++ inputs[0:2]  (out row r <- new_memory row r+2)
// out rows 0..509    = binary avg-pool hierarchy over memory rows 1024..1535 only:
//   P_l[i] = mean of 2^l consecutive "fallout" rows (fallout row t = memory row 512+t).
//   rows 254..381: P1[384..512) ; 382..509: P2[128..256) ; 126..189: P2[192..256)
//   190..253: P3[64..128) ; 62..93: P3[96..128) ; 94..125: P4[32..64) ; 30..45: P4[48..64)
//   level l>=5: primary row = 2^(10-l)-2+i for i in [2^(9-l),2^(10-l)),
//               secondary row = 2^(9-l)-2+i-3*2^(8-l) when i >= 3*2^(8-l) (l<9).
// Pairwise-sum tree + single 2^-l scale == reference's nested /2 bitwise (halving exact).
// Copy: one out row per block (row-uniform src select -> scalar), nt loads/stores
// (out never re-read; keep L2 for the pool's re-read of memory rows 1024..1535).

typedef __attribute__((ext_vector_type(4))) float f32x4;

#define B_    8
#define D_    2048
#define MEMR_ 2558
#define OUTR_ 2558
#define INR_  1024

#define POOL_DT     64                     // 64 col-tiles of 32 floats
#define POOL_BLOCKS (B_ * POOL_DT)         // 512
#define COPY_BLOCKS (B_ * 2048)            // one out row per block

__device__ __forceinline__ void write_row(float* dst, const float* s, float scale) {
  f32x4 o;
#pragma unroll
  for (int e = 0; e < 4; ++e) o[e] = s[e] * scale;
  __builtin_nontemporal_store(o, reinterpret_cast<f32x4*>(dst));
}

__global__ __launch_bounds__(256) void helix_kernel(
    const float* __restrict__ inputs,
    const float* __restrict__ memory,
    float* __restrict__ out) {
  __shared__ float lds[32 * 32];
  const int bid = blockIdx.x;
  const int tid = threadIdx.x;

  if (bid < POOL_BLOCKS) {
    // ---- pool-tree blocks: one (batch, 32-column tile) each ----
    const int b  = bid >> 6;           // / POOL_DT
    const int dt = bid & 63;
    const int q  = tid >> 3;           // 0..31 : row-group (16 fallout rows each)
    const int c  = tid & 7;            // 0..7  : float4 column within tile
    const int dcol = dt * 32 + c * 4;

    // tree source: fallout rows 512..1023 == memory rows 1024..1535
    const float* fall = memory + ((long)b * MEMR_ + 1024) * D_ + dcol;
    float* ob = out + (long)b * OUTR_ * D_ + dcol;

    float f[4], s1[4], s2[4], s3[4], s4[4];
    const float* rp = fall + (long)(q * 16) * D_;

#pragma unroll
    for (int j = 0; j < 16; ++j) {
      f32x4 u = *reinterpret_cast<const f32x4*>(rp + (long)j * D_);
#pragma unroll
      for (int e = 0; e < 4; ++e) f[e] = u[e];
      if ((j & 1) == 0) {
#pragma unroll
        for (int e = 0; e < 4; ++e) s1[e] = f[e];
      } else {
#pragma unroll
        for (int e = 0; e < 4; ++e) s1[e] += f[e];
        const int i1 = 256 + 8 * q + (j >> 1);            // P1 index in [256,512)
        if (i1 >= 384) write_row(ob + (long)(i1 - 130) * D_, s1, 0.5f);
        if ((j & 3) == 1) {
#pragma unroll
          for (int e = 0; e < 4; ++e) s2[e] = s1[e];
        } else {
#pragma unroll
          for (int e = 0; e < 4; ++e) s2[e] += s1[e];
          const int i2 = 128 + 4 * q + (j >> 2);          // P2 in [128,256)
          write_row(ob + (long)(254 + i2) * D_, s2, 0.25f);
          if (i2 >= 192) write_row(ob + (long)(i2 - 66) * D_, s2, 0.25f);
          if ((j & 7) == 3) {
#pragma unroll
            for (int e = 0; e < 4; ++e) s3[e] = s2[e];
          } else {
#pragma unroll
            for (int e = 0; e < 4; ++e) s3[e] += s2[e];
            const int i3 = 64 + 2 * q + (j >> 3);         // P3 in [64,128)
            write_row(ob + (long)(126 + i3) * D_, s3, 0.125f);
            if (i3 >= 96) write_row(ob + (long)(i3 - 34) * D_, s3, 0.125f);
            if (j == 7) {
#pragma unroll
              for (int e = 0; e < 4; ++e) s4[e] = s3[e];
            } else if (j == 15) {
#pragma unroll
              for (int e = 0; e < 4; ++e) s4[e] += s3[e];
              const int i4 = 32 + q;                      // P4 in [32,64)
              write_row(ob + (long)(62 + i4) * D_, s4, 0.0625f);
              if (i4 >= 48) write_row(ob + (long)(i4 - 18) * D_, s4, 0.0625f);
            }
          }
        }
      }
    }

    // stash 16-row sums, then LDS tree for levels 5..9
    float* myl = lds + q * 32 + c * 4;
#pragma unroll
    for (int e = 0; e < 4; ++e) myl[e] = s4[e];

    int nq = 16;
    float scale = 1.0f / 32.0f;
    for (int l = 5; l <= 9; ++l) {
      __syncthreads();
      float a[4], bb[4];
      const bool act = (q < nq);
      if (act) {
#pragma unroll
        for (int e = 0; e < 4; ++e) {
          a[e]  = lds[(2 * q) * 32 + c * 4 + e];
          bb[e] = lds[(2 * q + 1) * 32 + c * 4 + e];
        }
      }
      __syncthreads();
      if (act) {
#pragma unroll
        for (int e = 0; e < 4; ++e) a[e] += bb[e];
#pragma unroll
        for (int e = 0; e < 4; ++e) lds[q * 32 + c * 4 + e] = a[e];
        const int i = nq + q;                              // P_l index in [2^(9-l), 2^(10-l))
        write_row(ob + (long)((1 << (10 - l)) - 2 + i) * D_, a, scale);
        if (l < 9 && i >= (3 << (8 - l)))
          write_row(ob + (long)((1 << (9 - l)) - 2 + i - (3 << (8 - l))) * D_, a, scale);
      }
      nq >>= 1;
      scale *= 0.5f;
    }
  } else {
    // ---- copy blocks: one out row each (rows 510..2557) ----
    const int bid2 = bid - POOL_BLOCKS;
    const int b = bid2 >> 11;                       // / 2048
    const int j = bid2 & 2047;                      // row within short_memory (block-uniform)
    const float* src = (j < 2046)
        ? memory + ((long)b * MEMR_ + 512 + j) * D_
        : inputs + ((long)b * INR_ + (j - 2046)) * D_;
    float* dst = out + ((long)b * OUTR_ + 510 + j) * D_;
    const f32x4* s4p = reinterpret_cast<const f32x4*>(src);
    f32x4* d4p = reinterpret_cast<f32x4*>(dst);
    f32x4 v0 = __builtin_nontemporal_load(s4p + tid);
    f32x4 v1 = __builtin_nontemporal_load(s4p + tid + 256);
    __builtin_nontemporal_store(v0, d4p + tid);
    __builtin_nontemporal_store(v1, d4p + tid + 256);
  }
}

extern "C" void kernel_launch(void* const* d_in, const int* in_sizes, int n_in,
                              void* d_out, int out_size, void* d_ws, size_t ws_size,
                              hipStream_t stream) {
  const float* inputs = (const float*)d_in[0];
  const float* memory = (const float*)d_in[1];
  float* out = (float*)d_out;
  helix_kernel<<<dim3(POOL_BLOCKS + COPY_BLOCKS), dim3(256), 0, stream>>>(inputs, memory, out);
}